// Round 1
// baseline (1986.458 us; speedup 1.0000x reference)
//
#include <hip/hip_runtime.h>

#define N_NODES 50000
#define N_EDGES 1600000
#define R_WAV 4
#define D 128

// ---------------- GEMM: h = x @ W  ([N,128] @ [128,128]) ----------------
// 4 rows per block of 128 threads; thread j owns output column j for 4 rows.
// W reads are coalesced across lanes and L1/L2-resident (64 KB).
__global__ __launch_bounds__(128) void gemm_xw(const float* __restrict__ x,
                                               const float* __restrict__ W,
                                               float* __restrict__ h) {
    __shared__ float xs[4 * 128];
    const int j = threadIdx.x;
    const int row0 = blockIdx.x * 4;
    for (int t = j; t < 512; t += 128) xs[t] = x[(size_t)row0 * D + t];
    __syncthreads();
    float a0 = 0.f, a1 = 0.f, a2 = 0.f, a3 = 0.f;
#pragma unroll 8
    for (int k = 0; k < 128; ++k) {
        const float w = W[k * D + j];
        a0 += xs[k] * w;
        a1 += xs[128 + k] * w;
        a2 += xs[256 + k] * w;
        a3 += xs[384 + k] * w;
    }
    h[(size_t)(row0 + 0) * D + j] = a0;
    h[(size_t)(row0 + 1) * D + j] = a1;
    h[(size_t)(row0 + 2) * D + j] = a2;
    h[(size_t)(row0 + 3) * D + j] = a3;
}

// ---------------- CSR build step 1: histogram of rows ----------------
__global__ void hist_kernel(const int* __restrict__ rows, int* __restrict__ cnt) {
    const int i = blockIdx.x * blockDim.x + threadIdx.x;
    if (i < N_EDGES) atomicAdd(&cnt[rows[i]], 1);
}

// ---------------- CSR build step 2: exclusive scan (single block, 1024 thr) ---
// Reads counts from cnt_cursor, writes row_ptr[i] and rewrites cnt_cursor[i]
// with the same exclusive prefix (to be used as the scatter cursor).
__global__ __launch_bounds__(1024) void scan_kernel(int* __restrict__ cnt_cursor,
                                                    int* __restrict__ row_ptr) {
    __shared__ int wave_tot[16];
    __shared__ int wave_excl[17];
    __shared__ int block_off;
    const int tid = threadIdx.x;
    const int lane = tid & 63;
    const int w = tid >> 6;
    if (tid == 0) block_off = 0;
    __syncthreads();
    for (int base = 0; base < N_NODES; base += 1024) {
        const int i = base + tid;
        const int v = (i < N_NODES) ? cnt_cursor[i] : 0;
        int s = v;  // inclusive scan within wave
#pragma unroll
        for (int d = 1; d < 64; d <<= 1) {
            const int t = __shfl_up(s, d, 64);
            if (lane >= d) s += t;
        }
        if (lane == 63) wave_tot[w] = s;
        __syncthreads();
        if (w == 0) {  // scan the 16 wave totals in wave 0
            int t = (lane < 16) ? wave_tot[lane] : 0;
#pragma unroll
            for (int d = 1; d < 16; d <<= 1) {
                const int u = __shfl_up(t, d, 64);
                if (lane >= d) t += u;
            }
            if (lane < 16) wave_excl[lane] = t - wave_tot[lane];
            if (lane == 15) wave_excl[16] = t;
        }
        __syncthreads();
        const int excl = block_off + wave_excl[w] + (s - v);
        if (i < N_NODES) {
            row_ptr[i] = excl;
            cnt_cursor[i] = excl;
        }
        const int chunk_total = wave_excl[16];
        __syncthreads();  // everyone has read block_off / wave_excl
        if (tid == 0) block_off += chunk_total;
        __syncthreads();
    }
    if (tid == 0) row_ptr[N_NODES] = block_off;
}

// ---------------- CSR build step 3: scatter edges into sorted {col,val} -------
__global__ void scatter_kernel(const int* __restrict__ rows, const int* __restrict__ cols,
                               const float* __restrict__ vals, int* __restrict__ cursor,
                               int2* __restrict__ cv) {
    const int i = blockIdx.x * blockDim.x + threadIdx.x;
    if (i >= N_EDGES) return;
    const int r = rows[i];
    const int pos = atomicAdd(&cursor[r], 1);
    cv[pos] = make_int2(cols[i], __float_as_int(vals[i]));
}

// ---------------- SpMM pass 1: y[row] = filt[row] * sum_e val_e * h[col_e] ----
// One 64-lane wave per row; lane owns columns {2*lane, 2*lane+1} (float2).
// Unrolled by 2 for two independent gather chains per wave.
__global__ __launch_bounds__(256) void spmm1_kernel(const int* __restrict__ row_ptr,
                                                    const int2* __restrict__ cv,
                                                    const float* __restrict__ h,
                                                    const float* __restrict__ filt_r,
                                                    float* __restrict__ y) {
    const int row = blockIdx.x * 4 + (threadIdx.x >> 6);
    if (row >= N_NODES) return;
    const int lane = threadIdx.x & 63;
    int e = row_ptr[row];
    const int end = row_ptr[row + 1];
    float ax0 = 0.f, ay0 = 0.f, ax1 = 0.f, ay1 = 0.f;
    for (; e + 1 < end; e += 2) {
        const int2 cv0 = cv[e];
        const int2 cv1 = cv[e + 1];
        const float v0 = __int_as_float(cv0.y);
        const float v1 = __int_as_float(cv1.y);
        const float2 h0 = *(const float2*)(h + (size_t)(cv0.x * D + 2 * lane));
        const float2 h1 = *(const float2*)(h + (size_t)(cv1.x * D + 2 * lane));
        ax0 += v0 * h0.x; ay0 += v0 * h0.y;
        ax1 += v1 * h1.x; ay1 += v1 * h1.y;
    }
    if (e < end) {
        const int2 cv0 = cv[e];
        const float v0 = __int_as_float(cv0.y);
        const float2 h0 = *(const float2*)(h + (size_t)(cv0.x * D + 2 * lane));
        ax0 += v0 * h0.x; ay0 += v0 * h0.y;
    }
    const float f = filt_r[row];
    const float2 res = make_float2(f * (ax0 + ax1), f * (ay0 + ay1));
    *(float2*)(y + (size_t)row * D + 2 * lane) = res;
}

// ---------------- SpMM pass 2: out[row] (+)= sum_e val_e * y[col_e] -----------
template <bool FIRST>
__global__ __launch_bounds__(256) void spmm2_kernel(const int* __restrict__ row_ptr,
                                                    const int2* __restrict__ cv,
                                                    const float* __restrict__ y,
                                                    const float* __restrict__ bias,
                                                    float* __restrict__ out) {
    const int row = blockIdx.x * 4 + (threadIdx.x >> 6);
    if (row >= N_NODES) return;
    const int lane = threadIdx.x & 63;
    int e = row_ptr[row];
    const int end = row_ptr[row + 1];
    float ax0 = 0.f, ay0 = 0.f, ax1 = 0.f, ay1 = 0.f;
    for (; e + 1 < end; e += 2) {
        const int2 cv0 = cv[e];
        const int2 cv1 = cv[e + 1];
        const float v0 = __int_as_float(cv0.y);
        const float v1 = __int_as_float(cv1.y);
        const float2 y0 = *(const float2*)(y + (size_t)(cv0.x * D + 2 * lane));
        const float2 y1 = *(const float2*)(y + (size_t)(cv1.x * D + 2 * lane));
        ax0 += v0 * y0.x; ay0 += v0 * y0.y;
        ax1 += v1 * y1.x; ay1 += v1 * y1.y;
    }
    if (e < end) {
        const int2 cv0 = cv[e];
        const float v0 = __int_as_float(cv0.y);
        const float2 y0 = *(const float2*)(y + (size_t)(cv0.x * D + 2 * lane));
        ax0 += v0 * y0.x; ay0 += v0 * y0.y;
    }
    const float2 res = make_float2(ax0 + ax1, ay0 + ay1);
    float* op = out + (size_t)row * D + 2 * lane;
    if (FIRST) {
        const float2 b = *(const float2*)(bias + 2 * lane);
        *(float2*)op = make_float2(res.x + b.x, res.y + b.y);
    } else {
        const float2 cur = *(const float2*)op;
        *(float2*)op = make_float2(cur.x + res.x, cur.y + res.y);
    }
}

extern "C" void kernel_launch(void* const* d_in, const int* in_sizes, int n_in,
                              void* d_out, int out_size, void* d_ws, size_t ws_size,
                              hipStream_t stream) {
    const float* x    = (const float*)d_in[0];  // [N,128]
    const float* vals = (const float*)d_in[1];  // [R,E]
    const float* W    = (const float*)d_in[2];  // [128,128]
    const float* filt = (const float*)d_in[3];  // [R*N,1]
    const float* bias = (const float*)d_in[4];  // [128]
    const int*   rows = (const int*)d_in[5];    // [R,E]
    const int*   cols = (const int*)d_in[6];    // [R,E]
    float* out = (float*)d_out;                 // [N,128]

    char* ws = (char*)d_ws;
    float* h       = (float*)(ws);                         // 25.6 MB
    float* y       = (float*)(ws + 25600000);              // 25.6 MB
    int2*  cv      = (int2*)(ws + 51200000);               // 12.8 MB
    int*   row_ptr = (int*)(ws + 64000000);                // (N+1)*4 B
    int*   cursor  = (int*)(ws + 64000000 + 200016);       // N*4 B

    gemm_xw<<<N_NODES / 4, 128, 0, stream>>>(x, W, h);

    for (int r = 0; r < R_WAV; ++r) {
        const int*   rows_r = rows + (size_t)r * N_EDGES;
        const int*   cols_r = cols + (size_t)r * N_EDGES;
        const float* vals_r = vals + (size_t)r * N_EDGES;
        const float* filt_r = filt + (size_t)r * N_NODES;

        hipMemsetAsync(cursor, 0, N_NODES * sizeof(int), stream);
        hist_kernel<<<(N_EDGES + 255) / 256, 256, 0, stream>>>(rows_r, cursor);
        scan_kernel<<<1, 1024, 0, stream>>>(cursor, row_ptr);
        scatter_kernel<<<(N_EDGES + 255) / 256, 256, 0, stream>>>(rows_r, cols_r, vals_r,
                                                                  cursor, cv);
        spmm1_kernel<<<N_NODES / 4, 256, 0, stream>>>(row_ptr, cv, h, filt_r, y);
        if (r == 0)
            spmm2_kernel<true><<<N_NODES / 4, 256, 0, stream>>>(row_ptr, cv, y, bias, out);
        else
            spmm2_kernel<false><<<N_NODES / 4, 256, 0, stream>>>(row_ptr, cv, y, bias, out);
    }
}